// Round 2
// baseline (340.622 us; speedup 1.0000x reference)
//
#include <hip/hip_runtime.h>
#include <math.h>

#define NB 32
#define CB 64
#define HH 224
#define WW 224
#define PADP 2
#define HP (HH + 2*PADP)   // 228
#define WP (WW + 2*PADP)   // 228
#define HW (HH*WW)         // 50176
#define HWP (HP*WP)        // 51984
#define EPSV 1e-5f
#define CHUNKS 49          // HW / (256*4)

__device__ __forceinline__ float sigmoidf_(float v) { return 1.0f / (1.0f + expf(-v)); }

// ---------------- Pass 1 (new): one block per (n, spatial chunk of 1024 floats).
// Loops over all 64 channels keeping previous channel's float4 in a register,
// so x is read ~once (channel 63 twice). Writes per-chunk partial sums.
__global__ __launch_bounds__(256) void k_pool2(const float* __restrict__ x,
                                               float* __restrict__ partG,
                                               float* __restrict__ partX) {
    int b = blockIdx.x;
    int n = b / CHUNKS;
    int chunk = b - n * CHUNKS;
    int tid = threadIdx.x;
    int i = chunk * 1024 + tid * 4;          // element index in HW, float4-aligned, row-safe
    int h  = i / WW;
    int w0 = i - h * WW;
    float wh = 1.0f + (float)((h == 1) | (h == 2) | (h == HH-3) | (h == HH-2));
    float w_0 = wh * (1.0f + (float)((w0   == 1) | (w0   == 2) | (w0   == WW-3) | (w0   == WW-2)));
    float w_1 = wh * (1.0f + (float)((w0+1 == 1) | (w0+1 == 2) | (w0+1 == WW-3) | (w0+1 == WW-2)));
    float w_2 = wh * (1.0f + (float)((w0+2 == 1) | (w0+2 == 2) | (w0+2 == WW-3) | (w0+2 == WW-2)));
    float w_3 = wh * (1.0f + (float)((w0+3 == 1) | (w0+3 == 2) | (w0+3 == WW-3) | (w0+3 == WW-2)));

    const float* xn = x + (size_t)n * CB * HW;
    float4 prev = *(const float4*)(xn + (size_t)(CB-1) * HW + i);   // gate for c=0 is channel 63

    __shared__ float lds[CB][8];    // [channel][wave*2 + {G,X}]
    int wave = tid >> 6, lane = tid & 63;

    for (int c = 0; c < CB; ++c) {
        float4 cur = *(const float4*)(xn + (size_t)c * HW + i);
        float sG = w_0 * cur.x * sigmoidf_(prev.x)
                 + w_1 * cur.y * sigmoidf_(prev.y)
                 + w_2 * cur.z * sigmoidf_(prev.z)
                 + w_3 * cur.w * sigmoidf_(prev.w);
        float sX = w_0 * cur.x + w_1 * cur.y + w_2 * cur.z + w_3 * cur.w;
        for (int off = 32; off >= 1; off >>= 1) {
            sG += __shfl_xor(sG, off);
            sX += __shfl_xor(sX, off);
        }
        if (lane == 0) { lds[c][wave * 2] = sG; lds[c][wave * 2 + 1] = sX; }
        prev = cur;
    }
    __syncthreads();
    if (tid < 128) {
        int c = tid >> 1, v = tid & 1;
        float s = lds[c][v] + lds[c][2 + v] + lds[c][4 + v] + lds[c][6 + v];
        size_t idx = ((size_t)n * CB + c) * CHUNKS + chunk;
        if (v == 0) partG[idx] = s; else partX[idx] = s;
    }
}

// Stage 2: fold the 49 chunk-partials per (n,c).
__global__ __launch_bounds__(64) void k_red(const float* __restrict__ partG,
                                            const float* __restrict__ partX,
                                            float* __restrict__ pooled,
                                            float* __restrict__ cmean) {
    int bc = blockIdx.x;
    int t = threadIdx.x;
    float g = 0.f, xx = 0.f;
    if (t < CHUNKS) {
        g  = partG[(size_t)bc * CHUNKS + t];
        xx = partX[(size_t)bc * CHUNKS + t];
    }
    for (int off = 32; off >= 1; off >>= 1) {
        g  += __shfl_xor(g, off);
        xx += __shfl_xor(xx, off);
    }
    if (t == 0) {
        pooled[bc] = g  * (1.0f / (float)HWP);
        cmean[bc]  = xx * (1.0f / (float)HWP);
    }
}

// ---------------- Fallback pass 1 (old, reads x twice) if ws is tiny.
__global__ __launch_bounds__(256) void k_pool(const float* __restrict__ x,
                                              float* __restrict__ pooled,
                                              float* __restrict__ cmean) {
    int bc = blockIdx.x;
    int c  = bc & (CB - 1);
    int cm1 = (c + CB - 1) & (CB - 1);
    const float* xs = x + (size_t)bc * HW;
    const float* xg = x + (size_t)(bc - c + cm1) * HW;
    int tid = threadIdx.x;
    float sG = 0.f, sX = 0.f;
    for (int i = tid * 4; i < HW; i += 256 * 4) {
        float4 a = *(const float4*)(xs + i);
        float4 g = *(const float4*)(xg + i);
        int h  = i / WW;
        int w0 = i - h * WW;
        float wh = 1.0f + (float)((h == 1) | (h == 2) | (h == HH-3) | (h == HH-2));
        float w_0 = wh * (1.0f + (float)((w0   == 1) | (w0   == 2) | (w0   == WW-3) | (w0   == WW-2)));
        float w_1 = wh * (1.0f + (float)((w0+1 == 1) | (w0+1 == 2) | (w0+1 == WW-3) | (w0+1 == WW-2)));
        float w_2 = wh * (1.0f + (float)((w0+2 == 1) | (w0+2 == 2) | (w0+2 == WW-3) | (w0+2 == WW-2)));
        float w_3 = wh * (1.0f + (float)((w0+3 == 1) | (w0+3 == 2) | (w0+3 == WW-3) | (w0+3 == WW-2)));
        sG += w_0 * a.x * sigmoidf_(g.x);
        sG += w_1 * a.y * sigmoidf_(g.y);
        sG += w_2 * a.z * sigmoidf_(g.z);
        sG += w_3 * a.w * sigmoidf_(g.w);
        sX += w_0 * a.x + w_1 * a.y + w_2 * a.z + w_3 * a.w;
    }
    for (int off = 32; off >= 1; off >>= 1) {
        sG += __shfl_xor(sG, off);
        sX += __shfl_xor(sX, off);
    }
    __shared__ float lds[8];
    int wave = tid >> 6, lane = tid & 63;
    if (lane == 0) { lds[wave * 2] = sG; lds[wave * 2 + 1] = sX; }
    __syncthreads();
    if (tid == 0) {
        float g  = lds[0] + lds[2] + lds[4] + lds[6];
        float xx = lds[1] + lds[3] + lds[5] + lds[7];
        pooled[bc] = g  * (1.0f / (float)HWP);
        cmean[bc]  = xx * (1.0f / (float)HWP);
    }
}

// ---------------- BN (batch stats, biased var) + sigmoid -> scale.
__global__ __launch_bounds__(64) void k_bn(const float* __restrict__ pooled,
                                           const float* __restrict__ bnw,
                                           const float* __restrict__ bnb,
                                           float* __restrict__ scale) {
    int c = blockIdx.x;
    int t = threadIdx.x;
    float v = 0.f;
    if (t < 32) v = pooled[t * CB + c];
    float s = v;
    for (int off = 16; off >= 1; off >>= 1) s += __shfl_xor(s, off);
    float mu = s * (1.0f / 32.0f);
    float d = v - mu;
    float q = d * d;
    for (int off = 16; off >= 1; off >>= 1) q += __shfl_xor(q, off);
    float var = q * (1.0f / 32.0f);
    if (t < 32) {
        float normed = d * rsqrtf(var + EPSV) * bnw[c] + bnb[c];
        scale[t * CB + c] = sigmoidf_(normed);
    }
}

// ---------------- Output pass: block per (n, padded row), channel loop with
// register-carried gate value; exact GELU.
__global__ __launch_bounds__(256) void k_out(const float* __restrict__ x,
                                             const float* __restrict__ scale,
                                             const float* __restrict__ cmean,
                                             const float* __restrict__ post_scale,
                                             float* __restrict__ out) {
    int b  = blockIdx.x;            // n*HP + hp
    int n  = b / HP;
    int hp = b - n * HP;
    int rh = hp - PADP; rh = rh < 0 ? -rh : (rh >= HH ? 2*HH - 2 - rh : rh);
    int wp = threadIdx.x;
    if (wp >= WP) return;
    int rw = wp - PADP; rw = rw < 0 ? -rw : (rw >= WW ? 2*WW - 2 - rw : rw);

    float ps = post_scale[0];
    const float* xrow = x + (size_t)n * CB * HW + (size_t)rh * WW;
    float* orow = out + (size_t)n * CB * HWP + (size_t)hp * WP;
    const float* sc_row = scale + n * CB;
    const float* cm_row = cmean + n * CB;

    float prev = xrow[(size_t)(CB - 1) * HW + rw];
    for (int cc = 0; cc < CB; ++cc) {
        float cur = xrow[(size_t)cc * HW + rw];
        float g = cur * sigmoidf_(prev);
        float v = (g * sc_row[cc] + cm_row[cc]) * ps;
        float o = 0.5f * v * (1.0f + erff(v * 0.70710678118654752f));  // exact GELU
        orow[(size_t)cc * HWP + wp] = o;
        prev = cur;
    }
}

extern "C" void kernel_launch(void* const* d_in, const int* in_sizes, int n_in,
                              void* d_out, int out_size, void* d_ws, size_t ws_size,
                              hipStream_t stream) {
    const float* x   = (const float*)d_in[0];
    const float* bnw = (const float*)d_in[1];
    const float* bnb = (const float*)d_in[2];
    const float* ps  = (const float*)d_in[3];
    float* out = (float*)d_out;

    // ws layout: partG | partX | pooled | cmean | scale
    size_t npart = (size_t)NB * CB * CHUNKS;           // 100352
    size_t need  = (2 * npart + 3 * (size_t)NB * CB) * sizeof(float);  // ~827 KB

    float* partG  = (float*)d_ws;
    float* partX  = partG + npart;
    float* pooled = partX + npart;
    float* cmean  = pooled + NB * CB;
    float* scale  = cmean  + NB * CB;

    if (ws_size >= need) {
        k_pool2<<<NB * CHUNKS, 256, 0, stream>>>(x, partG, partX);
        k_red<<<NB * CB, 64, 0, stream>>>(partG, partX, pooled, cmean);
    } else {
        // small-ws fallback (reads x twice)
        pooled = (float*)d_ws;
        cmean  = pooled + NB * CB;
        scale  = cmean  + NB * CB;
        k_pool<<<NB * CB, 256, 0, stream>>>(x, pooled, cmean);
    }
    k_bn<<<CB, 64, 0, stream>>>(pooled, bnw, bnb, scale);
    k_out<<<NB * HP, 256, 0, stream>>>(x, scale, cmean, ps, out);
}

// Round 3
// 283.135 us; speedup vs baseline: 1.2030x; 1.2030x over previous
//
#include <hip/hip_runtime.h>
#include <math.h>

#define NB 32
#define CB 64
#define HH 224
#define WW 224
#define PADP 2
#define HP (HH + 2*PADP)   // 228
#define WP (WW + 2*PADP)   // 228
#define HW (HH*WW)         // 50176
#define HWP (HP*WP)        // 51984
#define EPSV 1e-5f
#define CHUNKS 49          // HW / (256*4)

// fast sigmoid: v_exp + v_rcp (error ~1e-6, budget is 3e-2)
__device__ __forceinline__ float fsig(float v) {
    float e = __expf(-v);
    return __builtin_amdgcn_rcpf(1.0f + e);
}
// tanh-form GELU: 0.5v(1+tanh(.79788(v+.044715v^3))) == v*sigmoid(1.59577v+.071355v^3)
__device__ __forceinline__ float fgelu(float v) {
    float t = v * (1.5957691216f + 0.0713548162f * v * v);
    return v * fsig(t);
}

// ---------------- Pass 1: one block per (n, spatial chunk of 1024 floats).
// Channel loop keeps previous channel's float4 in a register (GLU roll gate),
// so x is read ~once. Writes per-chunk partial sums.
__global__ __launch_bounds__(256) void k_pool2(const float* __restrict__ x,
                                               float* __restrict__ partG,
                                               float* __restrict__ partX) {
    int b = blockIdx.x;
    int n = b / CHUNKS;
    int chunk = b - n * CHUNKS;
    int tid = threadIdx.x;
    int i = chunk * 1024 + tid * 4;          // float4-aligned, row-safe (WW%4==0)
    int h  = i / WW;
    int w0 = i - h * WW;
    float wh = 1.0f + (float)((h == 1) | (h == 2) | (h == HH-3) | (h == HH-2));
    float w_0 = wh * (1.0f + (float)((w0   == 1) | (w0   == 2) | (w0   == WW-3) | (w0   == WW-2)));
    float w_1 = wh * (1.0f + (float)((w0+1 == 1) | (w0+1 == 2) | (w0+1 == WW-3) | (w0+1 == WW-2)));
    float w_2 = wh * (1.0f + (float)((w0+2 == 1) | (w0+2 == 2) | (w0+2 == WW-3) | (w0+2 == WW-2)));
    float w_3 = wh * (1.0f + (float)((w0+3 == 1) | (w0+3 == 2) | (w0+3 == WW-3) | (w0+3 == WW-2)));

    const float* xn = x + (size_t)n * CB * HW;
    float4 prev = *(const float4*)(xn + (size_t)(CB-1) * HW + i);   // gate for c=0 is channel 63

    __shared__ float lds[CB][8];    // [channel][wave*2 + {G,X}]
    int wave = tid >> 6, lane = tid & 63;

    for (int c = 0; c < CB; ++c) {
        float4 cur = *(const float4*)(xn + (size_t)c * HW + i);
        float sG = w_0 * cur.x * fsig(prev.x)
                 + w_1 * cur.y * fsig(prev.y)
                 + w_2 * cur.z * fsig(prev.z)
                 + w_3 * cur.w * fsig(prev.w);
        float sX = w_0 * cur.x + w_1 * cur.y + w_2 * cur.z + w_3 * cur.w;
        for (int off = 32; off >= 1; off >>= 1) {
            sG += __shfl_xor(sG, off);
            sX += __shfl_xor(sX, off);
        }
        if (lane == 0) { lds[c][wave * 2] = sG; lds[c][wave * 2 + 1] = sX; }
        prev = cur;
    }
    __syncthreads();
    if (tid < 128) {
        int c = tid >> 1, v = tid & 1;
        float s = lds[c][v] + lds[c][2 + v] + lds[c][4 + v] + lds[c][6 + v];
        size_t idx = ((size_t)n * CB + c) * CHUNKS + chunk;
        if (v == 0) partG[idx] = s; else partX[idx] = s;
    }
}

// Stage 2: fold the 49 chunk-partials per (n,c).
__global__ __launch_bounds__(64) void k_red(const float* __restrict__ partG,
                                            const float* __restrict__ partX,
                                            float* __restrict__ pooled,
                                            float* __restrict__ cmean) {
    int bc = blockIdx.x;
    int t = threadIdx.x;
    float g = 0.f, xx = 0.f;
    if (t < CHUNKS) {
        g  = partG[(size_t)bc * CHUNKS + t];
        xx = partX[(size_t)bc * CHUNKS + t];
    }
    for (int off = 32; off >= 1; off >>= 1) {
        g  += __shfl_xor(g, off);
        xx += __shfl_xor(xx, off);
    }
    if (t == 0) {
        pooled[bc] = g  * (1.0f / (float)HWP);
        cmean[bc]  = xx * (1.0f / (float)HWP);
    }
}

// ---------------- BN (batch stats, biased var) + sigmoid -> scale. Keep exact
// expf here (cost negligible, feeds everything).
__global__ __launch_bounds__(64) void k_bn(const float* __restrict__ pooled,
                                           const float* __restrict__ bnw,
                                           const float* __restrict__ bnb,
                                           float* __restrict__ scale) {
    int c = blockIdx.x;
    int t = threadIdx.x;
    float v = 0.f;
    if (t < 32) v = pooled[t * CB + c];
    float s = v;
    for (int off = 16; off >= 1; off >>= 1) s += __shfl_xor(s, off);
    float mu = s * (1.0f / 32.0f);
    float d = v - mu;
    float q = d * d;
    for (int off = 16; off >= 1; off >>= 1) q += __shfl_xor(q, off);
    float var = q * (1.0f / 32.0f);
    if (t < 32) {
        float normed = d * rsqrtf(var + EPSV) * bnw[c] + bnb[c];
        scale[t * CB + c] = 1.0f / (1.0f + expf(-normed));
    }
}

// ---------------- Output pass (vectorized): block per (n, padded row hp).
// Wave w handles channels [16w,16w+16). Lane l<56 owns float4 chunk rw=4l..4l+3
// of the unpadded row -> outputs wp=4l+2..4l+5 (contiguous map wp=rw+2).
// Edge outputs wp{0,1}=reflect(rw{2,1}) and wp{226,227}=reflect(rw{222,221})
// are identical values to interior outputs already computed in lanes 0/55.
__global__ __launch_bounds__(256) void k_out(const float* __restrict__ x,
                                             const float* __restrict__ scale,
                                             const float* __restrict__ cmean,
                                             const float* __restrict__ post_scale,
                                             float* __restrict__ out) {
    int b  = blockIdx.x;            // n*HP + hp
    int n  = b / HP;
    int hp = b - n * HP;
    int rh = hp - PADP; rh = rh < 0 ? -rh : (rh >= HH ? 2*HH - 2 - rh : rh);
    int wave = threadIdx.x >> 6;
    int lane = threadIdx.x & 63;
    bool act = lane < 56;
    float ps = post_scale[0];

    const float* xrow = x + (size_t)n * CB * HW + (size_t)rh * WW;
    const float* sc_row = scale + n * CB;
    const float* cm_row = cmean + n * CB;

    int c0 = wave * 16;
    int cg = (c0 + CB - 1) & (CB - 1);      // channel providing the gate for c0
    float4 prev = make_float4(0.f, 0.f, 0.f, 0.f);
    if (act) prev = *(const float4*)(xrow + (size_t)cg * HW + 4 * lane);

    for (int k = 0; k < 16; ++k) {
        int c = c0 + k;
        float4 cur = make_float4(0.f, 0.f, 0.f, 0.f);
        if (act) cur = *(const float4*)(xrow + (size_t)c * HW + 4 * lane);
        float scp = sc_row[c] * ps;         // wave-uniform
        float cmp = cm_row[c] * ps;
        float o0 = fgelu(fmaf(cur.x * fsig(prev.x), scp, cmp));
        float o1 = fgelu(fmaf(cur.y * fsig(prev.y), scp, cmp));
        float o2 = fgelu(fmaf(cur.z * fsig(prev.z), scp, cmp));
        float o3 = fgelu(fmaf(cur.w * fsig(prev.w), scp, cmp));
        float* orow = out + ((size_t)n * CB + c) * HWP + (size_t)hp * WP;
        if (act) {
            *(float2*)(orow + 4 * lane + 2) = make_float2(o0, o1);
            *(float2*)(orow + 4 * lane + 4) = make_float2(o2, o3);
            if (lane == 0)  *(float2*)(orow)       = make_float2(o2, o1);  // wp0<-rw2, wp1<-rw1
            if (lane == 55) *(float2*)(orow + 226) = make_float2(o2, o1);  // wp226<-rw222, wp227<-rw221
        }
        prev = cur;
    }
}

extern "C" void kernel_launch(void* const* d_in, const int* in_sizes, int n_in,
                              void* d_out, int out_size, void* d_ws, size_t ws_size,
                              hipStream_t stream) {
    const float* x   = (const float*)d_in[0];
    const float* bnw = (const float*)d_in[1];
    const float* bnb = (const float*)d_in[2];
    const float* ps  = (const float*)d_in[3];
    float* out = (float*)d_out;

    size_t npart = (size_t)NB * CB * CHUNKS;
    float* partG  = (float*)d_ws;
    float* partX  = partG + npart;
    float* pooled = partX + npart;
    float* cmean  = pooled + NB * CB;
    float* scale  = cmean  + NB * CB;

    k_pool2<<<NB * CHUNKS, 256, 0, stream>>>(x, partG, partX);
    k_red<<<NB * CB, 64, 0, stream>>>(partG, partX, pooled, cmean);
    k_bn<<<CB, 64, 0, stream>>>(pooled, bnw, bnb, scale);
    k_out<<<NB * HP, 256, 0, stream>>>(x, scale, cmean, ps, out);
}

// Round 5
// 272.549 us; speedup vs baseline: 1.2498x; 1.0388x over previous
//
#include <hip/hip_runtime.h>
#include <math.h>

#define NB 32
#define CB 64
#define HH 224
#define WW 224
#define PADP 2
#define HP (HH + 2*PADP)   // 228
#define WP (WW + 2*PADP)   // 228
#define HW (HH*WW)         // 50176
#define HWP (HP*WP)        // 51984
#define EPSV 1e-5f
#define CHUNKS 49          // HW / 1024

typedef float v4f __attribute__((ext_vector_type(4)));  // native vec for nontemporal store

// fast sigmoid: v_exp + v_rcp (error ~1e-6, budget is 3e-2)
__device__ __forceinline__ float fsig(float v) {
    float e = __expf(-v);
    return __builtin_amdgcn_rcpf(1.0f + e);
}
// tanh-form GELU == v*sigmoid(1.59577v + 0.071355v^3); max dev ~1e-3 << 3.3e-2 budget
__device__ __forceinline__ float fgelu(float v) {
    float t = v * (1.5957691216f + 0.0713548162f * v * v);
    return v * fsig(t);
}
__device__ __forceinline__ float edgew(int w) {
    return 1.0f + (float)((w == 1) | (w == 2) | (w == WW-3) | (w == WW-2));
}

// ---------------- Pass 1: block = (n, 1024-float spatial chunk). Each WAVE owns
// a 16-channel group over the whole chunk (4 float4/lane, strided 256 floats).
// 64-lane shfl reduce per channel (amortized over 4KB), lane 0 writes partials.
// No LDS, no syncthreads. Gate = previous channel carried in registers.
__global__ __launch_bounds__(256) void k_pool3(const float* __restrict__ x,
                                               float* __restrict__ partG,
                                               float* __restrict__ partX) {
    int b = blockIdx.x;
    int n = b / CHUNKS;
    int chunk = b - n * CHUNKS;
    int wave = threadIdx.x >> 6;
    int lane = threadIdx.x & 63;

    int p0 = chunk * 1024 + lane * 4;       // float4-aligned; WW%4==0 so row-safe
    float4 wgt[4];
    #pragma unroll
    for (int m = 0; m < 4; ++m) {
        int pm = p0 + m * 256;
        int h  = pm / WW;
        int w0 = pm - h * WW;
        float wh = 1.0f + (float)((h == 1) | (h == 2) | (h == HH-3) | (h == HH-2));
        wgt[m].x = wh * edgew(w0);
        wgt[m].y = wh * edgew(w0 + 1);
        wgt[m].z = wh * edgew(w0 + 2);
        wgt[m].w = wh * edgew(w0 + 3);
    }

    const float* xn = x + (size_t)n * CB * HW;
    int c0 = wave * 16;
    int cg = (c0 + CB - 1) & (CB - 1);      // gate channel for c0 (roll +1)
    float4 prev[4];
    #pragma unroll
    for (int m = 0; m < 4; ++m)
        prev[m] = *(const float4*)(xn + (size_t)cg * HW + p0 + m * 256);

    for (int k = 0; k < 16; ++k) {
        int c = c0 + k;
        float4 cur[4];
        #pragma unroll
        for (int m = 0; m < 4; ++m)
            cur[m] = *(const float4*)(xn + (size_t)c * HW + p0 + m * 256);
        float sG = 0.f, sX = 0.f;
        #pragma unroll
        for (int m = 0; m < 4; ++m) {
            sG += wgt[m].x * cur[m].x * fsig(prev[m].x);
            sG += wgt[m].y * cur[m].y * fsig(prev[m].y);
            sG += wgt[m].z * cur[m].z * fsig(prev[m].z);
            sG += wgt[m].w * cur[m].w * fsig(prev[m].w);
            sX += wgt[m].x * cur[m].x + wgt[m].y * cur[m].y
                + wgt[m].z * cur[m].z + wgt[m].w * cur[m].w;
            prev[m] = cur[m];
        }
        #pragma unroll
        for (int off = 32; off >= 1; off >>= 1) {
            sG += __shfl_xor(sG, off);
            sX += __shfl_xor(sX, off);
        }
        if (lane == 0) {
            size_t idx = ((size_t)n * CB + c) * CHUNKS + chunk;
            partG[idx] = sG;
            partX[idx] = sX;
        }
    }
}

// Stage 2: fold the 49 chunk-partials per (n,c).
__global__ __launch_bounds__(64) void k_red(const float* __restrict__ partG,
                                            const float* __restrict__ partX,
                                            float* __restrict__ pooled,
                                            float* __restrict__ cmean) {
    int bc = blockIdx.x;
    int t = threadIdx.x;
    float g = 0.f, xx = 0.f;
    if (t < CHUNKS) {
        g  = partG[(size_t)bc * CHUNKS + t];
        xx = partX[(size_t)bc * CHUNKS + t];
    }
    for (int off = 32; off >= 1; off >>= 1) {
        g  += __shfl_xor(g, off);
        xx += __shfl_xor(xx, off);
    }
    if (t == 0) {
        pooled[bc] = g  * (1.0f / (float)HWP);
        cmean[bc]  = xx * (1.0f / (float)HWP);
    }
}

// ---------------- BN (batch stats, biased var) + sigmoid -> scale.
__global__ __launch_bounds__(64) void k_bn(const float* __restrict__ pooled,
                                           const float* __restrict__ bnw,
                                           const float* __restrict__ bnb,
                                           float* __restrict__ scale) {
    int c = blockIdx.x;
    int t = threadIdx.x;
    float v = 0.f;
    if (t < 32) v = pooled[t * CB + c];
    float s = v;
    for (int off = 16; off >= 1; off >>= 1) s += __shfl_xor(s, off);
    float mu = s * (1.0f / 32.0f);
    float d = v - mu;
    float q = d * d;
    for (int off = 16; off >= 1; off >>= 1) q += __shfl_xor(q, off);
    float var = q * (1.0f / 32.0f);
    if (t < 32) {
        float normed = d * rsqrtf(var + EPSV) * bnw[c] + bnb[c];
        scale[t * CB + c] = 1.0f / (1.0f + expf(-normed));
    }
}

// ---------------- Output pass: block per (n, padded row hp); wave w handles
// channels [16w,16w+16). Lane l<56 loads aligned float4 rw=4l..4l+3, computes
// o0..o3; a shfl-up by one lane re-aligns values so lanes 0..56 each emit one
// ALIGNED nontemporal float4 store covering the padded row (edge reflection
// folded into lane 0 / lane 56 value selection).
__global__ __launch_bounds__(256) void k_out(const float* __restrict__ x,
                                             const float* __restrict__ scale,
                                             const float* __restrict__ cmean,
                                             const float* __restrict__ post_scale,
                                             float* __restrict__ out) {
    int b  = blockIdx.x;            // n*HP + hp
    int n  = b / HP;
    int hp = b - n * HP;
    int rh = hp - PADP; rh = rh < 0 ? -rh : (rh >= HH ? 2*HH - 2 - rh : rh);
    int wave = threadIdx.x >> 6;
    int lane = threadIdx.x & 63;
    bool act = lane < 56;
    float ps = post_scale[0];

    const float* xrow = x + (size_t)n * CB * HW + (size_t)rh * WW;
    const float* sc_row = scale + n * CB;
    const float* cm_row = cmean + n * CB;

    int c0 = wave * 16;
    int cg = (c0 + CB - 1) & (CB - 1);
    float4 prev = make_float4(0.f, 0.f, 0.f, 0.f);
    if (act) prev = *(const float4*)(xrow + (size_t)cg * HW + 4 * lane);

    for (int k = 0; k < 16; ++k) {
        int c = c0 + k;
        float4 cur = make_float4(0.f, 0.f, 0.f, 0.f);
        if (act) cur = *(const float4*)(xrow + (size_t)c * HW + 4 * lane);
        float scp = sc_row[c] * ps;         // wave-uniform
        float cmp = cm_row[c] * ps;
        float o0 = fgelu(fmaf(cur.x * fsig(prev.x), scp, cmp));
        float o1 = fgelu(fmaf(cur.y * fsig(prev.y), scp, cmp));
        float o2 = fgelu(fmaf(cur.z * fsig(prev.z), scp, cmp));
        float o3 = fgelu(fmaf(cur.w * fsig(prev.w), scp, cmp));
        // shift left-neighbor's (o1,o2,o3) in: lane l store covers wp=4l..4l+3
        float o1s = __shfl(o1, lane - 1);
        float o2s = __shfl(o2, lane - 1);
        float o3s = __shfl(o3, lane - 1);
        v4f st = { o2s, o3s, o0, o1 };          // interior: rw 4l-2..4l+1
        if (lane == 0)  st = (v4f){ o2, o1, o0, o1 };        // wp0<-rw2, wp1<-rw1, wp2<-rw0, wp3<-rw1
        if (lane == 56) st = (v4f){ o2s, o3s, o2s, o1s };    // wp224..227 <- rw222,223,222,221
        if (lane < 57) {
            float* orow = out + ((size_t)n * CB + c) * HWP + (size_t)hp * WP;
            __builtin_nontemporal_store(st, (v4f*)(orow + 4 * lane));
        }
        prev = cur;
    }
}

extern "C" void kernel_launch(void* const* d_in, const int* in_sizes, int n_in,
                              void* d_out, int out_size, void* d_ws, size_t ws_size,
                              hipStream_t stream) {
    const float* x   = (const float*)d_in[0];
    const float* bnw = (const float*)d_in[1];
    const float* bnb = (const float*)d_in[2];
    const float* ps  = (const float*)d_in[3];
    float* out = (float*)d_out;

    size_t npart = (size_t)NB * CB * CHUNKS;
    float* partG  = (float*)d_ws;
    float* partX  = partG + npart;
    float* pooled = partX + npart;
    float* cmean  = pooled + NB * CB;
    float* scale  = cmean  + NB * CB;

    k_pool3<<<NB * CHUNKS, 256, 0, stream>>>(x, partG, partX);
    k_red<<<NB * CB, 64, 0, stream>>>(partG, partX, pooled, cmean);
    k_bn<<<CB, 64, 0, stream>>>(pooled, bnw, bnb, scale);
    k_out<<<NB * HP, 256, 0, stream>>>(x, scale, cmean, ps, out);
}

// Round 6
// 253.130 us; speedup vs baseline: 1.3456x; 1.0767x over previous
//
#include <hip/hip_runtime.h>
#include <math.h>

#define NB 32
#define CB 64
#define HH 224
#define WW 224
#define PADP 2
#define HP (HH + 2*PADP)   // 228
#define WP (WW + 2*PADP)   // 228
#define HW (HH*WW)         // 50176
#define HWP (HP*WP)        // 51984
#define EPSV 1e-5f
#define CHUNKS 49          // HW / 1024

typedef float v4f __attribute__((ext_vector_type(4)));  // native vec for nontemporal ld/st

// fast sigmoid: v_exp + v_rcp (error ~1e-6, budget is 3e-2)
__device__ __forceinline__ float fsig(float v) {
    float e = __expf(-v);
    return __builtin_amdgcn_rcpf(1.0f + e);
}
// tanh-form GELU == v*sigmoid(1.59577v + 0.071355v^3); max dev ~1e-3 << 3.3e-2 budget
__device__ __forceinline__ float fgelu(float v) {
    float t = v * (1.5957691216f + 0.0713548162f * v * v);
    return v * fsig(t);
}
__device__ __forceinline__ float edgew(int w) {
    return 1.0f + (float)((w == 1) | (w == 2) | (w == WW-3) | (w == WW-2));
}

// ---------------- Pass 1: block = (n, 1024-float spatial chunk). Each WAVE owns
// a 16-channel group over the whole chunk (4 float4/lane). 64-lane shfl reduce
// per channel, lane 0 writes partials. No LDS/syncthreads. Register gate carry.
__global__ __launch_bounds__(256) void k_pool3(const float* __restrict__ x,
                                               float* __restrict__ partG,
                                               float* __restrict__ partX) {
    int b = blockIdx.x;
    int n = b / CHUNKS;
    int chunk = b - n * CHUNKS;
    int wave = threadIdx.x >> 6;
    int lane = threadIdx.x & 63;

    int p0 = chunk * 1024 + lane * 4;       // float4-aligned; WW%4==0 so row-safe
    float4 wgt[4];
    #pragma unroll
    for (int m = 0; m < 4; ++m) {
        int pm = p0 + m * 256;
        int h  = pm / WW;
        int w0 = pm - h * WW;
        float wh = 1.0f + (float)((h == 1) | (h == 2) | (h == HH-3) | (h == HH-2));
        wgt[m].x = wh * edgew(w0);
        wgt[m].y = wh * edgew(w0 + 1);
        wgt[m].z = wh * edgew(w0 + 2);
        wgt[m].w = wh * edgew(w0 + 3);
    }

    const float* xn = x + (size_t)n * CB * HW;
    int c0 = wave * 16;
    int cg = (c0 + CB - 1) & (CB - 1);      // gate channel for c0 (roll +1)
    float4 prev[4];
    #pragma unroll
    for (int m = 0; m < 4; ++m)
        prev[m] = *(const float4*)(xn + (size_t)cg * HW + p0 + m * 256);

    for (int k = 0; k < 16; ++k) {
        int c = c0 + k;
        float4 cur[4];
        #pragma unroll
        for (int m = 0; m < 4; ++m)
            cur[m] = *(const float4*)(xn + (size_t)c * HW + p0 + m * 256);
        float sG = 0.f, sX = 0.f;
        #pragma unroll
        for (int m = 0; m < 4; ++m) {
            sG += wgt[m].x * cur[m].x * fsig(prev[m].x);
            sG += wgt[m].y * cur[m].y * fsig(prev[m].y);
            sG += wgt[m].z * cur[m].z * fsig(prev[m].z);
            sG += wgt[m].w * cur[m].w * fsig(prev[m].w);
            sX += wgt[m].x * cur[m].x + wgt[m].y * cur[m].y
                + wgt[m].z * cur[m].z + wgt[m].w * cur[m].w;
            prev[m] = cur[m];
        }
        #pragma unroll
        for (int off = 32; off >= 1; off >>= 1) {
            sG += __shfl_xor(sG, off);
            sX += __shfl_xor(sX, off);
        }
        if (lane == 0) {
            size_t idx = ((size_t)n * CB + c) * CHUNKS + chunk;
            partG[idx] = sG;
            partX[idx] = sX;
        }
    }
}

// ---------------- Merged stats: fold 49 chunk-partials per (n,c), then BN
// (batch mean/biased var across n) + sigmoid -> scale; also writes cmean.
// One block per channel c; 8 threads per n.
__global__ __launch_bounds__(256) void k_stats(const float* __restrict__ partG,
                                               const float* __restrict__ partX,
                                               const float* __restrict__ bnw,
                                               const float* __restrict__ bnb,
                                               float* __restrict__ cmean,
                                               float* __restrict__ scale) {
    int c = blockIdx.x;
    int t = threadIdx.x;
    int n = t >> 3, j0 = t & 7;
    float g = 0.f, xx = 0.f;
    for (int j = j0; j < CHUNKS; j += 8) {
        size_t idx = ((size_t)n * CB + c) * CHUNKS + j;
        g  += partG[idx];
        xx += partX[idx];
    }
    #pragma unroll
    for (int off = 4; off >= 1; off >>= 1) {
        g  += __shfl_xor(g, off);
        xx += __shfl_xor(xx, off);
    }
    __shared__ float lG[NB];
    if (j0 == 0) {
        lG[n] = g;
        cmean[n * CB + c] = xx * (1.0f / (float)HWP);
    }
    __syncthreads();
    if (t < NB) {
        float p = lG[t] * (1.0f / (float)HWP);     // pooled[t][c]
        float s = p;
        #pragma unroll
        for (int off = 16; off >= 1; off >>= 1) s += __shfl_xor(s, off);
        float mu = s * (1.0f / 32.0f);
        float d = p - mu;
        float q = d * d;
        #pragma unroll
        for (int off = 16; off >= 1; off >>= 1) q += __shfl_xor(q, off);
        float var = q * (1.0f / 32.0f);
        float normed = d * rsqrtf(var + EPSV) * bnw[c] + bnb[c];
        scale[t * CB + c] = 1.0f / (1.0f + expf(-normed));
    }
}

// ---------------- Output pass: XCD-swizzled block per (n, padded row hp);
// wave w handles channels [16w,16w+16). Lane l<56 loads aligned float4
// rw=4l..4l+3 (nontemporal; single-use), computes o0..o3; shfl-up realigns so
// lanes 0..56 emit one ALIGNED nontemporal float4 store covering the padded row.
__global__ __launch_bounds__(256) void k_out(const float* __restrict__ x,
                                             const float* __restrict__ scale,
                                             const float* __restrict__ cmean,
                                             const float* __restrict__ post_scale,
                                             float* __restrict__ out) {
    // XCD swizzle: 7296 blocks = 8 XCDs x 912 contiguous (n,hp) rows (4 images each).
    int o = blockIdx.x;
    int w = (o & 7) * (NB * HP / 8) + (o >> 3);
    int n  = w / HP;
    int hp = w - n * HP;
    int rh = hp - PADP; rh = rh < 0 ? -rh : (rh >= HH ? 2*HH - 2 - rh : rh);
    int wave = threadIdx.x >> 6;
    int lane = threadIdx.x & 63;
    bool act = lane < 56;
    float ps = post_scale[0];

    const float* xrow = x + (size_t)n * CB * HW + (size_t)rh * WW;
    const float* sc_row = scale + n * CB;
    const float* cm_row = cmean + n * CB;

    int c0 = wave * 16;
    int cg = (c0 + CB - 1) & (CB - 1);
    v4f prev = {0.f, 0.f, 0.f, 0.f};
    if (act) prev = __builtin_nontemporal_load((const v4f*)(xrow + (size_t)cg * HW + 4 * lane));

    for (int k = 0; k < 16; ++k) {
        int c = c0 + k;
        v4f cur = {0.f, 0.f, 0.f, 0.f};
        if (act) cur = __builtin_nontemporal_load((const v4f*)(xrow + (size_t)c * HW + 4 * lane));
        float scp = sc_row[c] * ps;         // wave-uniform
        float cmp = cm_row[c] * ps;
        float o0 = fgelu(fmaf(cur.x * fsig(prev.x), scp, cmp));
        float o1 = fgelu(fmaf(cur.y * fsig(prev.y), scp, cmp));
        float o2 = fgelu(fmaf(cur.z * fsig(prev.z), scp, cmp));
        float o3 = fgelu(fmaf(cur.w * fsig(prev.w), scp, cmp));
        // shift left-neighbor's (o1,o2,o3) in: lane l store covers wp=4l..4l+3
        float o1s = __shfl(o1, lane - 1);
        float o2s = __shfl(o2, lane - 1);
        float o3s = __shfl(o3, lane - 1);
        v4f st = { o2s, o3s, o0, o1 };          // interior: rw 4l-2..4l+1
        if (lane == 0)  st = (v4f){ o2, o1, o0, o1 };        // wp0<-rw2, wp1<-rw1, wp2<-rw0, wp3<-rw1
        if (lane == 56) st = (v4f){ o2s, o3s, o2s, o1s };    // wp224..227 <- rw222,223,222,221
        if (lane < 57) {
            float* orow = out + ((size_t)n * CB + c) * HWP + (size_t)hp * WP;
            __builtin_nontemporal_store(st, (v4f*)(orow + 4 * lane));
        }
        prev = cur;
    }
}

extern "C" void kernel_launch(void* const* d_in, const int* in_sizes, int n_in,
                              void* d_out, int out_size, void* d_ws, size_t ws_size,
                              hipStream_t stream) {
    const float* x   = (const float*)d_in[0];
    const float* bnw = (const float*)d_in[1];
    const float* bnb = (const float*)d_in[2];
    const float* ps  = (const float*)d_in[3];
    float* out = (float*)d_out;

    size_t npart = (size_t)NB * CB * CHUNKS;
    float* partG  = (float*)d_ws;
    float* partX  = partG + npart;
    float* cmean  = partX + npart;
    float* scale  = cmean + NB * CB;

    k_pool3<<<NB * CHUNKS, 256, 0, stream>>>(x, partG, partX);
    k_stats<<<CB, 256, 0, stream>>>(partG, partX, bnw, bnb, cmean, scale);
    k_out<<<NB * HP, 256, 0, stream>>>(x, scale, cmean, ps, out);
}